// Round 5
// baseline (494.671 us; speedup 1.0000x reference)
//
#include <hip/hip_runtime.h>
#include <hip/hip_bf16.h>

#define BB 2
#define SS 2048
#define EE 1024
#define HH 16
#define HD 64

typedef __attribute__((ext_vector_type(8))) __bf16 bf16x8;
typedef __attribute__((ext_vector_type(4))) __bf16 bf16x4;
typedef __attribute__((ext_vector_type(4))) float f32x4;

__device__ __forceinline__ void split2(float x, __bf16& h, __bf16& l) {
    h = (__bf16)x;                 // RTNE
    l = (__bf16)(x - (float)h);    // residual
}

// ---------------- K0: elementwise fp32 -> bf16 hi/lo split ----------------
__global__ __launch_bounds__(256) void k_split(const float* __restrict__ in,
                                               __bf16* __restrict__ hi,
                                               __bf16* __restrict__ lo, int n4)
{
    int i = blockIdx.x * 256 + threadIdx.x;
    if (i >= n4) return;
    const float4 v = *(const float4*)(in + (size_t)i * 4);
    float t[4] = {v.x, v.y, v.z, v.w};
    bf16x4 h4, l4;
#pragma unroll
    for (int e = 0; e < 4; ++e) {
        __bf16 h, l; split2(t[e], h, l);
        h4[e] = h; l4[e] = l;
    }
    *(bf16x4*)(hi + (size_t)i * 4) = h4;
    *(bf16x4*)(lo + (size_t)i * 4) = l4;
}

// ---------------- K1: QKV projection (split-bf16 GEMM, fp32-accurate) -----
__global__ __launch_bounds__(256) void k_qkv(
    const __bf16* __restrict__ xhi, const __bf16* __restrict__ xlo,
    const __bf16* __restrict__ whi, const __bf16* __restrict__ wlo,
    const float* __restrict__ bqkv, const float* __restrict__ rel,
    __bf16* __restrict__ qhi_ws, __bf16* __restrict__ qlo_ws,
    __bf16* __restrict__ khi_ws, __bf16* __restrict__ klo_ws,
    __bf16* __restrict__ vt_ws)
{
    __shared__ __bf16 Ahi[128][72], Alo[128][72];
    __shared__ __bf16 Bhi[64][72],  Blo[64][72];

    const int tid = threadIdx.x;
    const int lane = tid & 63;
    const int wv = tid >> 6;
    const int m0 = blockIdx.y * 128;
    const int f0 = blockIdx.x * 64;
    const int wr = (wv >> 1) * 64, wc = (wv & 1) * 32;
    const int lr = lane & 15, lg = lane >> 4;

    f32x4 acc[4][2];
#pragma unroll
    for (int a = 0; a < 4; ++a)
#pragma unroll
        for (int b = 0; b < 2; ++b) acc[a][b] = (f32x4){0.f, 0.f, 0.f, 0.f};

    for (int kt = 0; kt < 16; ++kt) {
        const int k0 = kt * 64;
        __syncthreads();
        {   // stage A tile 128x64 (hi+lo)
            const int c = tid & 7, r0 = tid >> 3;
#pragma unroll
            for (int i = 0; i < 4; ++i) {
                const int row = r0 + i * 32;
                const size_t g = (size_t)(m0 + row) * EE + k0 + c * 8;
                *(bf16x8*)&Ahi[row][c * 8] = *(const bf16x8*)(xhi + g);
                *(bf16x8*)&Alo[row][c * 8] = *(const bf16x8*)(xlo + g);
            }
        }
        {   // stage B tile 64x64 (hi+lo)
            const int c = tid & 7, r0 = tid >> 3;
#pragma unroll
            for (int i = 0; i < 2; ++i) {
                const int row = r0 + i * 32;
                const size_t g = (size_t)(f0 + row) * EE + k0 + c * 8;
                *(bf16x8*)&Bhi[row][c * 8] = *(const bf16x8*)(whi + g);
                *(bf16x8*)&Blo[row][c * 8] = *(const bf16x8*)(wlo + g);
            }
        }
        __syncthreads();
#pragma unroll
        for (int ks = 0; ks < 2; ++ks) {
            const int koff = ks * 32 + lg * 8;
            bf16x8 ah[4], al[4], bh[2], bl[2];
#pragma unroll
            for (int rt = 0; rt < 4; ++rt) {
                ah[rt] = *(const bf16x8*)&Ahi[wr + rt * 16 + lr][koff];
                al[rt] = *(const bf16x8*)&Alo[wr + rt * 16 + lr][koff];
            }
#pragma unroll
            for (int ct = 0; ct < 2; ++ct) {
                bh[ct] = *(const bf16x8*)&Bhi[wc + ct * 16 + lr][koff];
                bl[ct] = *(const bf16x8*)&Blo[wc + ct * 16 + lr][koff];
            }
#pragma unroll
            for (int rt = 0; rt < 4; ++rt)
#pragma unroll
                for (int ct = 0; ct < 2; ++ct) {
                    acc[rt][ct] = __builtin_amdgcn_mfma_f32_16x16x32_bf16(ah[rt], bh[ct], acc[rt][ct], 0, 0, 0);
                    acc[rt][ct] = __builtin_amdgcn_mfma_f32_16x16x32_bf16(al[rt], bh[ct], acc[rt][ct], 0, 0, 0);
                    acc[rt][ct] = __builtin_amdgcn_mfma_f32_16x16x32_bf16(ah[rt], bl[ct], acc[rt][ct], 0, 0, 0);
                }
        }
    }

    const int blk = f0 >> 6;             // 0..47
    const int h = blk / 3, typ = blk % 3;
#pragma unroll
    for (int rt = 0; rt < 4; ++rt) {
        const int m = m0 + wr + rt * 16 + lg * 4;
        const int b = m >> 11, s = m & 2047;
#pragma unroll
        for (int ct = 0; ct < 2; ++ct) {
            const int d = wc + ct * 16 + lr;
            const float bq = bqkv[f0 + d];
            if (typ == 0) {
                const size_t base = ((size_t)(b * HH + h) * SS + s) * HD + d;
#pragma unroll
                for (int r = 0; r < 4; ++r) {
                    __bf16 hh, ll; split2(acc[rt][ct][r] + bq, hh, ll);
                    qhi_ws[base + (size_t)r * HD] = hh;
                    qlo_ws[base + (size_t)r * HD] = ll;
                }
            } else if (typ == 1) {
                const size_t base = ((size_t)(b * HH + h) * SS + s) * HD + d;
                const size_t rb = ((size_t)h * SS + s) * HD + d;
#pragma unroll
                for (int r = 0; r < 4; ++r) {
                    const float t = (acc[rt][ct][r] + bq) * 0.125f + rel[rb + (size_t)r * HD];
                    __bf16 hh, ll; split2(t, hh, ll);
                    khi_ws[base + (size_t)r * HD] = hh;
                    klo_ws[base + (size_t)r * HD] = ll;
                }
            } else {
                const size_t base = ((size_t)(b * HH + h) * HD + d) * SS + s;
                bf16x4 pk;
#pragma unroll
                for (int r = 0; r < 4; ++r) pk[r] = (__bf16)(acc[rt][ct][r] + bq);
                *(bf16x4*)&vt_ws[base] = pk;
            }
        }
    }
}

// ---------------- K2: fused two-pass attention, register-slim -------------
// Same algorithm/numerics as round 4, restructured for <=128 VGPR+AGPR so
// 4 waves/SIMD fit (__launch_bounds__(256,4)). K fragments consumed per
// 16-col chunk; V fragments in two half-batches.
__global__ __launch_bounds__(256, 4) void k_attn5(
    const __bf16* __restrict__ qhi_ws, const __bf16* __restrict__ qlo_ws,
    const __bf16* __restrict__ khi_ws, const __bf16* __restrict__ klo_ws,
    const __bf16* __restrict__ vt_ws,
    float* __restrict__ wts, __bf16* __restrict__ av_ws)
{
    __shared__ __bf16 P[4][32][72];   // wave-private P tiles; reused for PV combine
    __shared__ float ZX[4][32];       // Z partials exchange

    const int tid = threadIdx.x;
    const int lane = tid & 63;
    const int wv = tid >> 6;
    const int lr = lane & 15, lg = lane >> 4;
    const int rh = wv >> 1;           // row-half of the 64-row strip
    const int jh = wv & 1;            // j-half (16 j-tiles = 1024 cols)

    // XCD chunked swizzle: 1024 wgs; each XCD gets 128 consecutive wgids
    // = 4 bh values -> K/V (~3 MB) resident in that XCD's L2.
    const int wgid = ((blockIdx.x & 7) << 7) | (blockIdx.x >> 3);
    const int bh = wgid >> 5;
    const int q0 = (wgid & 31) * 64 + rh * 32;
    const size_t kvb = (size_t)bh * SS * HD;

    // q fragments (hi/lo): 8 frags = 32 VGPRs, live whole kernel
    bf16x8 qh[2][2], ql[2][2];
#pragma unroll
    for (int rg = 0; rg < 2; ++rg) {
        const size_t ro = kvb + (size_t)(q0 + rg * 16 + lr) * HD + lg * 8;
#pragma unroll
        for (int kk = 0; kk < 2; ++kk) {
            qh[rg][kk] = *(const bf16x8*)(qhi_ws + ro + kk * 32);
            ql[rg][kk] = *(const bf16x8*)(qlo_ws + ro + kk * 32);
        }
    }

    const __bf16* kh_base = khi_ws + kvb + (size_t)lr * HD + lg * 8;
    const __bf16* kl_base = klo_ws + kvb + (size_t)lr * HD + lg * 8;
    const int jt0 = jh * 16;

    // ---- pass 1: Z over this wave's j-half ----
    float z[2][4] = {{0.f,0.f,0.f,0.f},{0.f,0.f,0.f,0.f}};
    for (int t = 0; t < 16; ++t) {
        const size_t jo = (size_t)(jt0 + t) * (64 * HD);
#pragma unroll
        for (int cg = 0; cg < 4; ++cg) {
            const size_t co = jo + (size_t)cg * (16 * HD);
            const bf16x8 kh0 = *(const bf16x8*)(kh_base + co);
            const bf16x8 kh1 = *(const bf16x8*)(kh_base + co + 32);
            const bf16x8 kl0 = *(const bf16x8*)(kl_base + co);
            const bf16x8 kl1 = *(const bf16x8*)(kl_base + co + 32);
#pragma unroll
            for (int rg = 0; rg < 2; ++rg) {
                f32x4 u = (f32x4){0.f, 0.f, 0.f, 0.f};
                u = __builtin_amdgcn_mfma_f32_16x16x32_bf16(qh[rg][0], kh0, u, 0, 0, 0);
                u = __builtin_amdgcn_mfma_f32_16x16x32_bf16(qh[rg][1], kh1, u, 0, 0, 0);
                u = __builtin_amdgcn_mfma_f32_16x16x32_bf16(ql[rg][0], kh0, u, 0, 0, 0);
                u = __builtin_amdgcn_mfma_f32_16x16x32_bf16(ql[rg][1], kh1, u, 0, 0, 0);
                u = __builtin_amdgcn_mfma_f32_16x16x32_bf16(qh[rg][0], kl0, u, 0, 0, 0);
                u = __builtin_amdgcn_mfma_f32_16x16x32_bf16(qh[rg][1], kl1, u, 0, 0, 0);
#pragma unroll
                for (int r = 0; r < 4; ++r) z[rg][r] += __expf(u[r]);
            }
        }
    }
    // butterfly over the 16 lr lanes
#pragma unroll
    for (int m = 1; m < 16; m <<= 1)
#pragma unroll
        for (int rg = 0; rg < 2; ++rg)
#pragma unroll
            for (int r = 0; r < 4; ++r) z[rg][r] += __shfl_xor(z[rg][r], m, 64);
    // exchange partial Z with the partner wave (other j-half)
    if (lr == 0) {
#pragma unroll
        for (int rg = 0; rg < 2; ++rg)
#pragma unroll
            for (int r = 0; r < 4; ++r) ZX[wv][rg * 16 + lg * 4 + r] = z[rg][r];
    }
    __syncthreads();
    float rz[2][4];
#pragma unroll
    for (int rg = 0; rg < 2; ++rg)
#pragma unroll
        for (int r = 0; r < 4; ++r)
            rz[rg][r] = 1.0f / (z[rg][r] + ZX[wv ^ 1][rg * 16 + lg * 4 + r]);

    // ---- pass 2: weights + PV over this wave's j-half ----
    f32x4 pv[2][4];
#pragma unroll
    for (int rg = 0; rg < 2; ++rg)
#pragma unroll
        for (int dg = 0; dg < 4; ++dg) pv[rg][dg] = (f32x4){0.f, 0.f, 0.f, 0.f};

    const __bf16* vt_base = vt_ws + kvb + (size_t)lr * SS + lg * 8;
    float* wbase = wts + ((size_t)bh * SS + q0) * SS;

    for (int t = 0; t < 16; ++t) {
        const int jt = jt0 + t;
        const int j0 = jt * 64;
        const size_t jo = (size_t)jt * (64 * HD);
        // QK + exp + P-write, per 16-col chunk (transients die each cg)
#pragma unroll
        for (int cg = 0; cg < 4; ++cg) {
            const size_t co = jo + (size_t)cg * (16 * HD);
            const bf16x8 kh0 = *(const bf16x8*)(kh_base + co);
            const bf16x8 kh1 = *(const bf16x8*)(kh_base + co + 32);
            const bf16x8 kl0 = *(const bf16x8*)(kl_base + co);
            const bf16x8 kl1 = *(const bf16x8*)(kl_base + co + 32);
#pragma unroll
            for (int rg = 0; rg < 2; ++rg) {
                f32x4 u = (f32x4){0.f, 0.f, 0.f, 0.f};
                u = __builtin_amdgcn_mfma_f32_16x16x32_bf16(qh[rg][0], kh0, u, 0, 0, 0);
                u = __builtin_amdgcn_mfma_f32_16x16x32_bf16(qh[rg][1], kh1, u, 0, 0, 0);
                u = __builtin_amdgcn_mfma_f32_16x16x32_bf16(ql[rg][0], kh0, u, 0, 0, 0);
                u = __builtin_amdgcn_mfma_f32_16x16x32_bf16(ql[rg][1], kh1, u, 0, 0, 0);
                u = __builtin_amdgcn_mfma_f32_16x16x32_bf16(qh[rg][0], kl0, u, 0, 0, 0);
                u = __builtin_amdgcn_mfma_f32_16x16x32_bf16(qh[rg][1], kl1, u, 0, 0, 0);
#pragma unroll
                for (int r = 0; r < 4; ++r)
                    P[wv][rg * 16 + lg * 4 + r][cg * 16 + lr] =
                        (__bf16)(__expf(u[r]) * rz[rg][r]);
            }
        }
        // PV: P rows from LDS, V in two half-batches
        {
            const bf16x8 pa00 = *(const bf16x8*)&P[wv][lr][lg * 8];
            const bf16x8 pa01 = *(const bf16x8*)&P[wv][lr][32 + lg * 8];
            const bf16x8 pa10 = *(const bf16x8*)&P[wv][16 + lr][lg * 8];
            const bf16x8 pa11 = *(const bf16x8*)&P[wv][16 + lr][32 + lg * 8];
#pragma unroll
            for (int dp = 0; dp < 2; ++dp) {
                const __bf16* vp = vt_base + (size_t)(dp * 2) * (16 * SS) + j0;
                const bf16x8 v00 = *(const bf16x8*)vp;
                const bf16x8 v01 = *(const bf16x8*)(vp + 32);
                const bf16x8 v10 = *(const bf16x8*)(vp + 16 * SS);
                const bf16x8 v11 = *(const bf16x8*)(vp + 16 * SS + 32);
                pv[0][dp * 2]     = __builtin_amdgcn_mfma_f32_16x16x32_bf16(pa00, v00, pv[0][dp * 2], 0, 0, 0);
                pv[0][dp * 2]     = __builtin_amdgcn_mfma_f32_16x16x32_bf16(pa01, v01, pv[0][dp * 2], 0, 0, 0);
                pv[0][dp * 2 + 1] = __builtin_amdgcn_mfma_f32_16x16x32_bf16(pa00, v10, pv[0][dp * 2 + 1], 0, 0, 0);
                pv[0][dp * 2 + 1] = __builtin_amdgcn_mfma_f32_16x16x32_bf16(pa01, v11, pv[0][dp * 2 + 1], 0, 0, 0);
                pv[1][dp * 2]     = __builtin_amdgcn_mfma_f32_16x16x32_bf16(pa10, v00, pv[1][dp * 2], 0, 0, 0);
                pv[1][dp * 2]     = __builtin_amdgcn_mfma_f32_16x16x32_bf16(pa11, v01, pv[1][dp * 2], 0, 0, 0);
                pv[1][dp * 2 + 1] = __builtin_amdgcn_mfma_f32_16x16x32_bf16(pa10, v10, pv[1][dp * 2 + 1], 0, 0, 0);
                pv[1][dp * 2 + 1] = __builtin_amdgcn_mfma_f32_16x16x32_bf16(pa11, v11, pv[1][dp * 2 + 1], 0, 0, 0);
            }
        }
        // weights: coalesced float4 stores from the P tile (bf16-rounded)
#pragma unroll
        for (int it = 0; it < 8; ++it) {
            const int row = it * 4 + lg;
            const bf16x4 u = *(const bf16x4*)&P[wv][row][lr * 4];
            float4 o;
            o.x = (float)u[0]; o.y = (float)u[1]; o.z = (float)u[2]; o.w = (float)u[3];
            *(float4*)(wbase + (size_t)row * SS + j0 + lr * 4) = o;
        }
    }

    // ---- combine PV partials across j-halves (reuse P region as f32) ----
    __syncthreads();                      // all waves done with their P tiles
    float* X = (float*)&P[0][0][0];       // 2 pairs x 32x64 f32 = 16 KB
    if (jh == 1) {
#pragma unroll
        for (int rg = 0; rg < 2; ++rg)
#pragma unroll
            for (int dg = 0; dg < 4; ++dg)
#pragma unroll
                for (int r = 0; r < 4; ++r)
                    X[rh * 2048 + (rg * 16 + lg * 4 + r) * 64 + dg * 16 + lr] = pv[rg][dg][r];
    }
    __syncthreads();
    if (jh == 0) {
        const int b = bh >> 4, h = bh & 15;
#pragma unroll
        for (int rg = 0; rg < 2; ++rg)
#pragma unroll
            for (int dg = 0; dg < 4; ++dg)
#pragma unroll
                for (int r = 0; r < 4; ++r) {
                    const float av = pv[rg][dg][r] +
                        X[rh * 2048 + (rg * 16 + lg * 4 + r) * 64 + dg * 16 + lr];
                    const int s = q0 + rg * 16 + lg * 4 + r;
                    av_ws[((size_t)(b * SS + s)) * EE + h * HD + dg * 16 + lr] = (__bf16)av;
                }
    }
}

// ---------------- K3: out projection (plain bf16) -------------------------
__global__ __launch_bounds__(256) void k_oproj(
    const __bf16* __restrict__ av_ws, const float* __restrict__ w_out,
    const float* __restrict__ b_out, float* __restrict__ out)
{
    __shared__ __bf16 Abf[128][72];
    __shared__ __bf16 Bbf[64][72];
    const int tid = threadIdx.x;
    const int lane = tid & 63;
    const int wv = tid >> 6;
    const int m0 = blockIdx.y * 128, f0 = blockIdx.x * 64;
    const int wr = (wv >> 1) * 64, wc = (wv & 1) * 32;
    const int lr = lane & 15, lg = lane >> 4;

    f32x4 acc[4][2];
#pragma unroll
    for (int a = 0; a < 4; ++a)
#pragma unroll
        for (int b = 0; b < 2; ++b) acc[a][b] = (f32x4){0.f, 0.f, 0.f, 0.f};

    for (int kt = 0; kt < 16; ++kt) {
        const int k0 = kt * 64;
        __syncthreads();
        {
            const int c = tid & 7, r0 = tid >> 3;
#pragma unroll
            for (int i = 0; i < 4; ++i) {
                const int row = r0 + i * 32;
                *(bf16x8*)&Abf[row][c * 8] =
                    *(const bf16x8*)(av_ws + (size_t)(m0 + row) * EE + k0 + c * 8);
            }
        }
        {
            const int c = tid & 15, r0 = tid >> 4;
#pragma unroll
            for (int i = 0; i < 4; ++i) {
                const int row = r0 + i * 16;
                const float4 v = *(const float4*)(w_out + (size_t)(f0 + row) * EE + k0 + c * 4);
                bf16x4 pk;
                pk[0] = (__bf16)v.x; pk[1] = (__bf16)v.y;
                pk[2] = (__bf16)v.z; pk[3] = (__bf16)v.w;
                *(bf16x4*)&Bbf[row][c * 4] = pk;
            }
        }
        __syncthreads();
#pragma unroll
        for (int ks = 0; ks < 2; ++ks) {
            const int koff = ks * 32 + lg * 8;
            bf16x8 a[4], b[2];
#pragma unroll
            for (int rt = 0; rt < 4; ++rt) a[rt] = *(const bf16x8*)&Abf[wr + rt * 16 + lr][koff];
#pragma unroll
            for (int ct = 0; ct < 2; ++ct) b[ct] = *(const bf16x8*)&Bbf[wc + ct * 16 + lr][koff];
#pragma unroll
            for (int rt = 0; rt < 4; ++rt)
#pragma unroll
                for (int ct = 0; ct < 2; ++ct)
                    acc[rt][ct] = __builtin_amdgcn_mfma_f32_16x16x32_bf16(a[rt], b[ct], acc[rt][ct], 0, 0, 0);
        }
    }
#pragma unroll
    for (int rt = 0; rt < 4; ++rt) {
        const int m = m0 + wr + rt * 16 + lg * 4;
#pragma unroll
        for (int ct = 0; ct < 2; ++ct) {
            const int f = f0 + wc + ct * 16 + lr;
            const float bo = b_out[f];
#pragma unroll
            for (int r = 0; r < 4; ++r)
                out[(size_t)(m + r) * EE + f] = acc[rt][ct][r] + bo;
        }
    }
}

extern "C" void kernel_launch(void* const* d_in, const int* in_sizes, int n_in,
                              void* d_out, int out_size, void* d_ws, size_t ws_size,
                              hipStream_t stream)
{
    const float* x    = (const float*)d_in[0];
    const float* wqkv = (const float*)d_in[1];
    const float* bqkv = (const float*)d_in[2];
    const float* wo   = (const float*)d_in[3];
    const float* bo   = (const float*)d_in[4];
    const float* rel  = (const float*)d_in[5];

    float* out = (float*)d_out;
    float* wts = out + (size_t)BB * SS * EE;      // weights region, written by K2

    const size_t NQ = (size_t)BB * HH * SS * HD;  // 4M elements
    __bf16* qhi_ws = (__bf16*)d_ws;               // 8 MB each
    __bf16* qlo_ws = qhi_ws + NQ;
    __bf16* khi_ws = qlo_ws + NQ;
    __bf16* klo_ws = khi_ws + NQ;
    __bf16* vt_ws  = klo_ws + NQ;
    __bf16* av_ws  = vt_ws + NQ;                  // ws total: 48 MB

    // hi/lo splits of x and w_qkv live in the weights output region:
    // fully consumed by K1 before K2 overwrites it. (28 MB of 512 MB.)
    __bf16* xhi = (__bf16*)wts;
    __bf16* xlo = xhi + (size_t)BB * SS * EE;
    __bf16* whi = xlo + (size_t)BB * SS * EE;
    __bf16* wlo = whi + (size_t)3 * EE * EE;

    k_split<<<dim3((BB * SS * EE) / 1024), 256, 0, stream>>>(x, xhi, xlo, (BB * SS * EE) / 4);
    k_split<<<dim3((3 * EE * EE) / 1024), 256, 0, stream>>>(wqkv, whi, wlo, (3 * EE * EE) / 4);
    k_qkv<<<dim3(48, 32), 256, 0, stream>>>(xhi, xlo, whi, wlo, bqkv, rel,
                                            qhi_ws, qlo_ws, khi_ws, klo_ws, vt_ws);
    k_attn5<<<dim3(1024), 256, 0, stream>>>(qhi_ws, qlo_ws, khi_ws, klo_ws,
                                            vt_ws, wts, av_ws);
    k_oproj<<<dim3(EE / 64, (BB * SS) / 128), 256, 0, stream>>>(av_ws, wo, bo, out);
}

// Round 6
// 473.689 us; speedup vs baseline: 1.0443x; 1.0443x over previous
//
#include <hip/hip_runtime.h>
#include <hip/hip_bf16.h>

#define BB 2
#define SS 2048
#define EE 1024
#define HH 16
#define HD 64

typedef __attribute__((ext_vector_type(8))) __bf16 bf16x8;
typedef __attribute__((ext_vector_type(4))) __bf16 bf16x4;
typedef __attribute__((ext_vector_type(4))) float f32x4;

__device__ __forceinline__ void split2(float x, __bf16& h, __bf16& l) {
    h = (__bf16)x;                 // RTNE
    l = (__bf16)(x - (float)h);    // residual
}

// ---------------- K0: elementwise fp32 -> bf16 hi/lo split ----------------
__global__ __launch_bounds__(256) void k_split(const float* __restrict__ in,
                                               __bf16* __restrict__ hi,
                                               __bf16* __restrict__ lo, int n4)
{
    int i = blockIdx.x * 256 + threadIdx.x;
    if (i >= n4) return;
    const float4 v = *(const float4*)(in + (size_t)i * 4);
    float t[4] = {v.x, v.y, v.z, v.w};
    bf16x4 h4, l4;
#pragma unroll
    for (int e = 0; e < 4; ++e) {
        __bf16 h, l; split2(t[e], h, l);
        h4[e] = h; l4[e] = l;
    }
    *(bf16x4*)(hi + (size_t)i * 4) = h4;
    *(bf16x4*)(lo + (size_t)i * 4) = l4;
}

// ---------------- K1: QKV projection (split-bf16 GEMM, fp32-accurate) -----
__global__ __launch_bounds__(256) void k_qkv(
    const __bf16* __restrict__ xhi, const __bf16* __restrict__ xlo,
    const __bf16* __restrict__ whi, const __bf16* __restrict__ wlo,
    const float* __restrict__ bqkv, const float* __restrict__ rel,
    __bf16* __restrict__ qhi_ws, __bf16* __restrict__ qlo_ws,
    __bf16* __restrict__ khi_ws, __bf16* __restrict__ klo_ws,
    __bf16* __restrict__ vt_ws)
{
    __shared__ __bf16 Ahi[128][72], Alo[128][72];
    __shared__ __bf16 Bhi[64][72],  Blo[64][72];

    const int tid = threadIdx.x;
    const int lane = tid & 63;
    const int wv = tid >> 6;
    const int m0 = blockIdx.y * 128;
    const int f0 = blockIdx.x * 64;
    const int wr = (wv >> 1) * 64, wc = (wv & 1) * 32;
    const int lr = lane & 15, lg = lane >> 4;

    f32x4 acc[4][2];
#pragma unroll
    for (int a = 0; a < 4; ++a)
#pragma unroll
        for (int b = 0; b < 2; ++b) acc[a][b] = (f32x4){0.f, 0.f, 0.f, 0.f};

    for (int kt = 0; kt < 16; ++kt) {
        const int k0 = kt * 64;
        __syncthreads();
        {   // stage A tile 128x64 (hi+lo)
            const int c = tid & 7, r0 = tid >> 3;
#pragma unroll
            for (int i = 0; i < 4; ++i) {
                const int row = r0 + i * 32;
                const size_t g = (size_t)(m0 + row) * EE + k0 + c * 8;
                *(bf16x8*)&Ahi[row][c * 8] = *(const bf16x8*)(xhi + g);
                *(bf16x8*)&Alo[row][c * 8] = *(const bf16x8*)(xlo + g);
            }
        }
        {   // stage B tile 64x64 (hi+lo)
            const int c = tid & 7, r0 = tid >> 3;
#pragma unroll
            for (int i = 0; i < 2; ++i) {
                const int row = r0 + i * 32;
                const size_t g = (size_t)(f0 + row) * EE + k0 + c * 8;
                *(bf16x8*)&Bhi[row][c * 8] = *(const bf16x8*)(whi + g);
                *(bf16x8*)&Blo[row][c * 8] = *(const bf16x8*)(wlo + g);
            }
        }
        __syncthreads();
#pragma unroll
        for (int ks = 0; ks < 2; ++ks) {
            const int koff = ks * 32 + lg * 8;
            bf16x8 ah[4], al[4], bh[2], bl[2];
#pragma unroll
            for (int rt = 0; rt < 4; ++rt) {
                ah[rt] = *(const bf16x8*)&Ahi[wr + rt * 16 + lr][koff];
                al[rt] = *(const bf16x8*)&Alo[wr + rt * 16 + lr][koff];
            }
#pragma unroll
            for (int ct = 0; ct < 2; ++ct) {
                bh[ct] = *(const bf16x8*)&Bhi[wc + ct * 16 + lr][koff];
                bl[ct] = *(const bf16x8*)&Blo[wc + ct * 16 + lr][koff];
            }
#pragma unroll
            for (int rt = 0; rt < 4; ++rt)
#pragma unroll
                for (int ct = 0; ct < 2; ++ct) {
                    acc[rt][ct] = __builtin_amdgcn_mfma_f32_16x16x32_bf16(ah[rt], bh[ct], acc[rt][ct], 0, 0, 0);
                    acc[rt][ct] = __builtin_amdgcn_mfma_f32_16x16x32_bf16(al[rt], bh[ct], acc[rt][ct], 0, 0, 0);
                    acc[rt][ct] = __builtin_amdgcn_mfma_f32_16x16x32_bf16(ah[rt], bl[ct], acc[rt][ct], 0, 0, 0);
                }
        }
    }

    const int blk = f0 >> 6;             // 0..47
    const int h = blk / 3, typ = blk % 3;
#pragma unroll
    for (int rt = 0; rt < 4; ++rt) {
        const int m = m0 + wr + rt * 16 + lg * 4;
        const int b = m >> 11, s = m & 2047;
#pragma unroll
        for (int ct = 0; ct < 2; ++ct) {
            const int d = wc + ct * 16 + lr;
            const float bq = bqkv[f0 + d];
            if (typ == 0) {
                const size_t base = ((size_t)(b * HH + h) * SS + s) * HD + d;
#pragma unroll
                for (int r = 0; r < 4; ++r) {
                    __bf16 hh, ll; split2(acc[rt][ct][r] + bq, hh, ll);
                    qhi_ws[base + (size_t)r * HD] = hh;
                    qlo_ws[base + (size_t)r * HD] = ll;
                }
            } else if (typ == 1) {
                const size_t base = ((size_t)(b * HH + h) * SS + s) * HD + d;
                const size_t rb = ((size_t)h * SS + s) * HD + d;
#pragma unroll
                for (int r = 0; r < 4; ++r) {
                    const float t = (acc[rt][ct][r] + bq) * 0.125f + rel[rb + (size_t)r * HD];
                    __bf16 hh, ll; split2(t, hh, ll);
                    khi_ws[base + (size_t)r * HD] = hh;
                    klo_ws[base + (size_t)r * HD] = ll;
                }
            } else {
                const size_t base = ((size_t)(b * HH + h) * HD + d) * SS + s;
                bf16x4 pk;
#pragma unroll
                for (int r = 0; r < 4; ++r) pk[r] = (__bf16)(acc[rt][ct][r] + bq);
                *(bf16x4*)&vt_ws[base] = pk;
            }
        }
    }
}

// ---------------- K2: two-pass attention, burst weights writes ------------
// Round-3 shape (512 blocks, 4 independent waves x 32 q-rows, barrier-free,
// full per-tile K-frag ILP) + NEW: normalized P staged per-wave in LDS for
// 4 j-tiles, weights then written as 1KB-contiguous full-wave float4 bursts
// (was: 256B row-chunks -> ~1.5 TB/s effective write BW).
__global__ __launch_bounds__(256) void k_attn6(
    const __bf16* __restrict__ qhi_ws, const __bf16* __restrict__ qlo_ws,
    const __bf16* __restrict__ khi_ws, const __bf16* __restrict__ klo_ws,
    const __bf16* __restrict__ vt_ws,
    float* __restrict__ wts, __bf16* __restrict__ av_ws)
{
    __shared__ __bf16 P4[4][32][264];   // per-wave 32 rows x 256 cols (+8 pad)

    const int tid = threadIdx.x;
    const int lane = tid & 63;
    const int wv = tid >> 6;
    const int lr = lane & 15, lg = lane >> 4;

    // XCD-aware swizzle: 512 wgs, 64 per XCD -> 4 bh per XCD (K/V L2-resident)
    const int wgid = ((blockIdx.x & 7) << 6) | (blockIdx.x >> 3);
    const int bh = wgid >> 4;
    const int q0 = (wgid & 15) * 128 + wv * 32;
    const size_t kvb = (size_t)bh * SS * HD;

    // q fragments (hi/lo), 2 row-groups x 2 k-chunks
    bf16x8 qh[2][2], ql[2][2];
#pragma unroll
    for (int rg = 0; rg < 2; ++rg) {
        const size_t ro = kvb + (size_t)(q0 + rg * 16 + lr) * HD + lg * 8;
#pragma unroll
        for (int kk = 0; kk < 2; ++kk) {
            qh[rg][kk] = *(const bf16x8*)(qhi_ws + ro + kk * 32);
            ql[rg][kk] = *(const bf16x8*)(qlo_ws + ro + kk * 32);
        }
    }

    const __bf16* kh_base = khi_ws + kvb + (size_t)lr * HD + lg * 8;
    const __bf16* kl_base = klo_ws + kvb + (size_t)lr * HD + lg * 8;

    // ---- pass 1: Z ----
    float z[2][4] = {{0.f,0.f,0.f,0.f},{0.f,0.f,0.f,0.f}};
    for (int jt = 0; jt < 32; ++jt) {
        const size_t jo = (size_t)jt * (64 * HD);
        bf16x8 kh[4][2], kl[4][2];
#pragma unroll
        for (int cg = 0; cg < 4; ++cg) {
            const size_t co = jo + (size_t)cg * (16 * HD);
#pragma unroll
            for (int kk = 0; kk < 2; ++kk) {
                kh[cg][kk] = *(const bf16x8*)(kh_base + co + kk * 32);
                kl[cg][kk] = *(const bf16x8*)(kl_base + co + kk * 32);
            }
        }
        f32x4 a[2][4];
#pragma unroll
        for (int rg = 0; rg < 2; ++rg)
#pragma unroll
            for (int cg = 0; cg < 4; ++cg) {
                f32x4 u = (f32x4){0.f, 0.f, 0.f, 0.f};
                u = __builtin_amdgcn_mfma_f32_16x16x32_bf16(qh[rg][0], kh[cg][0], u, 0, 0, 0);
                u = __builtin_amdgcn_mfma_f32_16x16x32_bf16(qh[rg][1], kh[cg][1], u, 0, 0, 0);
                u = __builtin_amdgcn_mfma_f32_16x16x32_bf16(ql[rg][0], kh[cg][0], u, 0, 0, 0);
                u = __builtin_amdgcn_mfma_f32_16x16x32_bf16(ql[rg][1], kh[cg][1], u, 0, 0, 0);
                u = __builtin_amdgcn_mfma_f32_16x16x32_bf16(qh[rg][0], kl[cg][0], u, 0, 0, 0);
                u = __builtin_amdgcn_mfma_f32_16x16x32_bf16(qh[rg][1], kl[cg][1], u, 0, 0, 0);
                a[rg][cg] = u;
            }
#pragma unroll
        for (int rg = 0; rg < 2; ++rg)
#pragma unroll
            for (int cg = 0; cg < 4; ++cg)
#pragma unroll
                for (int r = 0; r < 4; ++r) z[rg][r] += __expf(a[rg][cg][r]);
    }
    // butterfly over the 16 lr lanes -> every lane holds Z for its rows
#pragma unroll
    for (int m = 1; m < 16; m <<= 1)
#pragma unroll
        for (int rg = 0; rg < 2; ++rg)
#pragma unroll
            for (int r = 0; r < 4; ++r) z[rg][r] += __shfl_xor(z[rg][r], m, 64);
    float rz[2][4];
#pragma unroll
    for (int rg = 0; rg < 2; ++rg)
#pragma unroll
        for (int r = 0; r < 4; ++r) rz[rg][r] = 1.0f / z[rg][r];

    // ---- pass 2: weights (staged, burst-written) + PV ----
    f32x4 pv[2][4];
#pragma unroll
    for (int rg = 0; rg < 2; ++rg)
#pragma unroll
        for (int dg = 0; dg < 4; ++dg) pv[rg][dg] = (f32x4){0.f, 0.f, 0.f, 0.f};

    const __bf16* vt_base = vt_ws + kvb + (size_t)lr * SS + lg * 8;
    float* wbase = wts + ((size_t)bh * SS + q0) * SS;

    for (int jb = 0; jb < 8; ++jb) {
#pragma unroll
        for (int t = 0; t < 4; ++t) {
            const int jt = jb * 4 + t;
            const int j0 = jt * 64;
            const size_t jo = (size_t)jt * (64 * HD);
            bf16x8 kh[4][2], kl[4][2];
#pragma unroll
            for (int cg = 0; cg < 4; ++cg) {
                const size_t co = jo + (size_t)cg * (16 * HD);
#pragma unroll
                for (int kk = 0; kk < 2; ++kk) {
                    kh[cg][kk] = *(const bf16x8*)(kh_base + co + kk * 32);
                    kl[cg][kk] = *(const bf16x8*)(kl_base + co + kk * 32);
                }
            }
            f32x4 a[2][4];
#pragma unroll
            for (int rg = 0; rg < 2; ++rg)
#pragma unroll
                for (int cg = 0; cg < 4; ++cg) {
                    f32x4 u = (f32x4){0.f, 0.f, 0.f, 0.f};
                    u = __builtin_amdgcn_mfma_f32_16x16x32_bf16(qh[rg][0], kh[cg][0], u, 0, 0, 0);
                    u = __builtin_amdgcn_mfma_f32_16x16x32_bf16(qh[rg][1], kh[cg][1], u, 0, 0, 0);
                    u = __builtin_amdgcn_mfma_f32_16x16x32_bf16(ql[rg][0], kh[cg][0], u, 0, 0, 0);
                    u = __builtin_amdgcn_mfma_f32_16x16x32_bf16(ql[rg][1], kh[cg][1], u, 0, 0, 0);
                    u = __builtin_amdgcn_mfma_f32_16x16x32_bf16(qh[rg][0], kl[cg][0], u, 0, 0, 0);
                    u = __builtin_amdgcn_mfma_f32_16x16x32_bf16(qh[rg][1], kl[cg][1], u, 0, 0, 0);
                    a[rg][cg] = u;
                }
            // normalized P -> per-wave LDS strip (transpose bounce + staging)
#pragma unroll
            for (int rg = 0; rg < 2; ++rg)
#pragma unroll
                for (int cg = 0; cg < 4; ++cg)
#pragma unroll
                    for (int r = 0; r < 4; ++r)
                        P4[wv][rg * 16 + lg * 4 + r][t * 64 + cg * 16 + lr] =
                            (__bf16)(__expf(a[rg][cg][r]) * rz[rg][r]);
            // V fragments + PV (A-frags from the staged strip)
            bf16x8 vb[4][2];
#pragma unroll
            for (int dg = 0; dg < 4; ++dg)
#pragma unroll
                for (int kk = 0; kk < 2; ++kk)
                    vb[dg][kk] = *(const bf16x8*)(vt_base + (size_t)dg * (16 * SS) + j0 + kk * 32);
#pragma unroll
            for (int rg = 0; rg < 2; ++rg) {
                bf16x8 pa0 = *(const bf16x8*)&P4[wv][rg * 16 + lr][t * 64 + lg * 8];
                bf16x8 pa1 = *(const bf16x8*)&P4[wv][rg * 16 + lr][t * 64 + 32 + lg * 8];
#pragma unroll
                for (int dg = 0; dg < 4; ++dg) {
                    pv[rg][dg] = __builtin_amdgcn_mfma_f32_16x16x32_bf16(pa0, vb[dg][0], pv[rg][dg], 0, 0, 0);
                    pv[rg][dg] = __builtin_amdgcn_mfma_f32_16x16x32_bf16(pa1, vb[dg][1], pv[rg][dg], 0, 0, 0);
                }
            }
        }
        // burst: 32 rows x 1KB contiguous full-wave stores
        const int jc = jb * 256;
#pragma unroll 4
        for (int it = 0; it < 32; ++it) {
            const bf16x4 u = *(const bf16x4*)&P4[wv][it][lane * 4];
            float4 o;
            o.x = (float)u[0]; o.y = (float)u[1]; o.z = (float)u[2]; o.w = (float)u[3];
            *(float4*)(wbase + (size_t)it * SS + jc + lane * 4) = o;
        }
    }

    {   // av -> bf16 ws [B][S][E]
        const int b = bh >> 4, h = bh & 15;
#pragma unroll
        for (int rg = 0; rg < 2; ++rg)
#pragma unroll
            for (int dg = 0; dg < 4; ++dg)
#pragma unroll
                for (int r = 0; r < 4; ++r) {
                    const int s = q0 + rg * 16 + lg * 4 + r;
                    av_ws[((size_t)(b * SS + s)) * EE + h * HD + dg * 16 + lr] =
                        (__bf16)pv[rg][dg][r];
                }
    }
}

// ---------------- K3: out projection (plain bf16) -------------------------
__global__ __launch_bounds__(256) void k_oproj(
    const __bf16* __restrict__ av_ws, const float* __restrict__ w_out,
    const float* __restrict__ b_out, float* __restrict__ out)
{
    __shared__ __bf16 Abf[128][72];
    __shared__ __bf16 Bbf[64][72];
    const int tid = threadIdx.x;
    const int lane = tid & 63;
    const int wv = tid >> 6;
    const int m0 = blockIdx.y * 128, f0 = blockIdx.x * 64;
    const int wr = (wv >> 1) * 64, wc = (wv & 1) * 32;
    const int lr = lane & 15, lg = lane >> 4;

    f32x4 acc[4][2];
#pragma unroll
    for (int a = 0; a < 4; ++a)
#pragma unroll
        for (int b = 0; b < 2; ++b) acc[a][b] = (f32x4){0.f, 0.f, 0.f, 0.f};

    for (int kt = 0; kt < 16; ++kt) {
        const int k0 = kt * 64;
        __syncthreads();
        {
            const int c = tid & 7, r0 = tid >> 3;
#pragma unroll
            for (int i = 0; i < 4; ++i) {
                const int row = r0 + i * 32;
                *(bf16x8*)&Abf[row][c * 8] =
                    *(const bf16x8*)(av_ws + (size_t)(m0 + row) * EE + k0 + c * 8);
            }
        }
        {
            const int c = tid & 15, r0 = tid >> 4;
#pragma unroll
            for (int i = 0; i < 4; ++i) {
                const int row = r0 + i * 16;
                const float4 v = *(const float4*)(w_out + (size_t)(f0 + row) * EE + k0 + c * 4);
                bf16x4 pk;
                pk[0] = (__bf16)v.x; pk[1] = (__bf16)v.y;
                pk[2] = (__bf16)v.z; pk[3] = (__bf16)v.w;
                *(bf16x4*)&Bbf[row][c * 4] = pk;
            }
        }
        __syncthreads();
#pragma unroll
        for (int ks = 0; ks < 2; ++ks) {
            const int koff = ks * 32 + lg * 8;
            bf16x8 a[4], b[2];
#pragma unroll
            for (int rt = 0; rt < 4; ++rt) a[rt] = *(const bf16x8*)&Abf[wr + rt * 16 + lr][koff];
#pragma unroll
            for (int ct = 0; ct < 2; ++ct) b[ct] = *(const bf16x8*)&Bbf[wc + ct * 16 + lr][koff];
#pragma unroll
            for (int rt = 0; rt < 4; ++rt)
#pragma unroll
                for (int ct = 0; ct < 2; ++ct)
                    acc[rt][ct] = __builtin_amdgcn_mfma_f32_16x16x32_bf16(a[rt], b[ct], acc[rt][ct], 0, 0, 0);
        }
    }
#pragma unroll
    for (int rt = 0; rt < 4; ++rt) {
        const int m = m0 + wr + rt * 16 + lg * 4;
#pragma unroll
        for (int ct = 0; ct < 2; ++ct) {
            const int f = f0 + wc + ct * 16 + lr;
            const float bo = b_out[f];
#pragma unroll
            for (int r = 0; r < 4; ++r)
                out[(size_t)(m + r) * EE + f] = acc[rt][ct][r] + bo;
        }
    }
}

extern "C" void kernel_launch(void* const* d_in, const int* in_sizes, int n_in,
                              void* d_out, int out_size, void* d_ws, size_t ws_size,
                              hipStream_t stream)
{
    const float* x    = (const float*)d_in[0];
    const float* wqkv = (const float*)d_in[1];
    const float* bqkv = (const float*)d_in[2];
    const float* wo   = (const float*)d_in[3];
    const float* bo   = (const float*)d_in[4];
    const float* rel  = (const float*)d_in[5];

    float* out = (float*)d_out;
    float* wts = out + (size_t)BB * SS * EE;      // weights region, written by K2

    const size_t NQ = (size_t)BB * HH * SS * HD;  // 4M elements
    __bf16* qhi_ws = (__bf16*)d_ws;               // 8 MB each
    __bf16* qlo_ws = qhi_ws + NQ;
    __bf16* khi_ws = qlo_ws + NQ;
    __bf16* klo_ws = khi_ws + NQ;
    __bf16* vt_ws  = klo_ws + NQ;
    __bf16* av_ws  = vt_ws + NQ;                  // ws total: 48 MB

    // hi/lo splits of x and w_qkv live in the weights output region:
    // fully consumed by K1 before K2 overwrites it. (28 MB of 512 MB.)
    __bf16* xhi = (__bf16*)wts;
    __bf16* xlo = xhi + (size_t)BB * SS * EE;
    __bf16* whi = xlo + (size_t)BB * SS * EE;
    __bf16* wlo = whi + (size_t)3 * EE * EE;

    k_split<<<dim3((BB * SS * EE) / 1024), 256, 0, stream>>>(x, xhi, xlo, (BB * SS * EE) / 4);
    k_split<<<dim3((3 * EE * EE) / 1024), 256, 0, stream>>>(wqkv, whi, wlo, (3 * EE * EE) / 4);
    k_qkv<<<dim3(48, 32), 256, 0, stream>>>(xhi, xlo, whi, wlo, bqkv, rel,
                                            qhi_ws, qlo_ws, khi_ws, klo_ws, vt_ws);
    k_attn6<<<dim3(512), 256, 0, stream>>>(qhi_ws, qlo_ws, khi_ws, klo_ws,
                                           vt_ws, wts, av_ws);
    k_oproj<<<dim3(EE / 64, (BB * SS) / 128), 256, 0, stream>>>(av_ws, wo, bo, out);
}

// Round 7
// 342.783 us; speedup vs baseline: 1.4431x; 1.3819x over previous
//
#include <hip/hip_runtime.h>
#include <hip/hip_bf16.h>

#define BB 2
#define SS 2048
#define EE 1024
#define HH 16
#define HD 64

typedef __attribute__((ext_vector_type(8))) __bf16 bf16x8;
typedef __attribute__((ext_vector_type(4))) __bf16 bf16x4;
typedef __attribute__((ext_vector_type(4))) float f32x4;

__device__ __forceinline__ void split2(float x, __bf16& h, __bf16& l) {
    h = (__bf16)x;                 // RTNE
    l = (__bf16)(x - (float)h);    // residual
}

// ---------------- K0: elementwise fp32 -> bf16 hi/lo split ----------------
__global__ __launch_bounds__(256) void k_split(const float* __restrict__ in,
                                               __bf16* __restrict__ hi,
                                               __bf16* __restrict__ lo, int n4)
{
    int i = blockIdx.x * 256 + threadIdx.x;
    if (i >= n4) return;
    const float4 v = *(const float4*)(in + (size_t)i * 4);
    float t[4] = {v.x, v.y, v.z, v.w};
    bf16x4 h4, l4;
#pragma unroll
    for (int e = 0; e < 4; ++e) {
        __bf16 h, l; split2(t[e], h, l);
        h4[e] = h; l4[e] = l;
    }
    *(bf16x4*)(hi + (size_t)i * 4) = h4;
    *(bf16x4*)(lo + (size_t)i * 4) = l4;
}

// ---------------- K1: QKV projection (split-bf16 GEMM, fp32-accurate) -----
__global__ __launch_bounds__(256) void k_qkv(
    const __bf16* __restrict__ xhi, const __bf16* __restrict__ xlo,
    const __bf16* __restrict__ whi, const __bf16* __restrict__ wlo,
    const float* __restrict__ bqkv, const float* __restrict__ rel,
    __bf16* __restrict__ qhi_ws, __bf16* __restrict__ qlo_ws,
    __bf16* __restrict__ khi_ws, __bf16* __restrict__ klo_ws,
    __bf16* __restrict__ vt_ws)
{
    __shared__ __bf16 Ahi[128][72], Alo[128][72];
    __shared__ __bf16 Bhi[64][72],  Blo[64][72];

    const int tid = threadIdx.x;
    const int lane = tid & 63;
    const int wv = tid >> 6;
    const int m0 = blockIdx.y * 128;
    const int f0 = blockIdx.x * 64;
    const int wr = (wv >> 1) * 64, wc = (wv & 1) * 32;
    const int lr = lane & 15, lg = lane >> 4;

    f32x4 acc[4][2];
#pragma unroll
    for (int a = 0; a < 4; ++a)
#pragma unroll
        for (int b = 0; b < 2; ++b) acc[a][b] = (f32x4){0.f, 0.f, 0.f, 0.f};

    for (int kt = 0; kt < 16; ++kt) {
        const int k0 = kt * 64;
        __syncthreads();
        {   // stage A tile 128x64 (hi+lo)
            const int c = tid & 7, r0 = tid >> 3;
#pragma unroll
            for (int i = 0; i < 4; ++i) {
                const int row = r0 + i * 32;
                const size_t g = (size_t)(m0 + row) * EE + k0 + c * 8;
                *(bf16x8*)&Ahi[row][c * 8] = *(const bf16x8*)(xhi + g);
                *(bf16x8*)&Alo[row][c * 8] = *(const bf16x8*)(xlo + g);
            }
        }
        {   // stage B tile 64x64 (hi+lo)
            const int c = tid & 7, r0 = tid >> 3;
#pragma unroll
            for (int i = 0; i < 2; ++i) {
                const int row = r0 + i * 32;
                const size_t g = (size_t)(f0 + row) * EE + k0 + c * 8;
                *(bf16x8*)&Bhi[row][c * 8] = *(const bf16x8*)(whi + g);
                *(bf16x8*)&Blo[row][c * 8] = *(const bf16x8*)(wlo + g);
            }
        }
        __syncthreads();
#pragma unroll
        for (int ks = 0; ks < 2; ++ks) {
            const int koff = ks * 32 + lg * 8;
            bf16x8 ah[4], al[4], bh[2], bl[2];
#pragma unroll
            for (int rt = 0; rt < 4; ++rt) {
                ah[rt] = *(const bf16x8*)&Ahi[wr + rt * 16 + lr][koff];
                al[rt] = *(const bf16x8*)&Alo[wr + rt * 16 + lr][koff];
            }
#pragma unroll
            for (int ct = 0; ct < 2; ++ct) {
                bh[ct] = *(const bf16x8*)&Bhi[wc + ct * 16 + lr][koff];
                bl[ct] = *(const bf16x8*)&Blo[wc + ct * 16 + lr][koff];
            }
#pragma unroll
            for (int rt = 0; rt < 4; ++rt)
#pragma unroll
                for (int ct = 0; ct < 2; ++ct) {
                    acc[rt][ct] = __builtin_amdgcn_mfma_f32_16x16x32_bf16(ah[rt], bh[ct], acc[rt][ct], 0, 0, 0);
                    acc[rt][ct] = __builtin_amdgcn_mfma_f32_16x16x32_bf16(al[rt], bh[ct], acc[rt][ct], 0, 0, 0);
                    acc[rt][ct] = __builtin_amdgcn_mfma_f32_16x16x32_bf16(ah[rt], bl[ct], acc[rt][ct], 0, 0, 0);
                }
        }
    }

    const int blk = f0 >> 6;             // 0..47
    const int h = blk / 3, typ = blk % 3;
#pragma unroll
    for (int rt = 0; rt < 4; ++rt) {
        const int m = m0 + wr + rt * 16 + lg * 4;
        const int b = m >> 11, s = m & 2047;
#pragma unroll
        for (int ct = 0; ct < 2; ++ct) {
            const int d = wc + ct * 16 + lr;
            const float bq = bqkv[f0 + d];
            if (typ == 0) {
                const size_t base = ((size_t)(b * HH + h) * SS + s) * HD + d;
#pragma unroll
                for (int r = 0; r < 4; ++r) {
                    __bf16 hh, ll; split2(acc[rt][ct][r] + bq, hh, ll);
                    qhi_ws[base + (size_t)r * HD] = hh;
                    qlo_ws[base + (size_t)r * HD] = ll;
                }
            } else if (typ == 1) {
                const size_t base = ((size_t)(b * HH + h) * SS + s) * HD + d;
                const size_t rb = ((size_t)h * SS + s) * HD + d;
#pragma unroll
                for (int r = 0; r < 4; ++r) {
                    const float t = (acc[rt][ct][r] + bq) * 0.125f + rel[rb + (size_t)r * HD];
                    __bf16 hh, ll; split2(t, hh, ll);
                    khi_ws[base + (size_t)r * HD] = hh;
                    klo_ws[base + (size_t)r * HD] = ll;
                }
            } else {
                const size_t base = ((size_t)(b * HH + h) * HD + d) * SS + s;
                bf16x4 pk;
#pragma unroll
                for (int r = 0; r < 4; ++r) pk[r] = (__bf16)(acc[rt][ct][r] + bq);
                *(bf16x4*)&vt_ws[base] = pk;
            }
        }
    }
}

// ---------------- K2: two-pass attention, block-shared K/V in LDS ---------
// 8 waves x 32 q-rows = 256 rows per block, one bh. Per 64-j tile: K hi/lo
// (and V in pass 2) staged ONCE into LDS and shared by all 8 waves -> K-read
// traffic drops 8x (2.6 GB -> 320 MB) below the measured ~7.4 TB/s L2/fabric
// wall. Staging is register-prefetched (next tile's global loads issue right
// after the ds_write barrier, hiding latency under compute). Per-wave math,
// Z order, P/PV/weights identical to round 6.
__global__ __launch_bounds__(512, 2) void k_attn7(
    const __bf16* __restrict__ qhi_ws, const __bf16* __restrict__ qlo_ws,
    const __bf16* __restrict__ khi_ws, const __bf16* __restrict__ klo_ws,
    const __bf16* __restrict__ vt_ws,
    float* __restrict__ wts, __bf16* __restrict__ av_ws)
{
    __shared__ __bf16 KH[64][72], KL[64][72], VTS[64][72];  // 27.6 KB
    __shared__ __bf16 P[8][32][72];                         // 36.9 KB

    const int tid = threadIdx.x;
    const int lane = tid & 63;
    const int wv = tid >> 6;          // 0..7
    const int lr = lane & 15, lg = lane >> 4;

    // XCD swizzle: 256 blocks; XCD k gets wgid k*32..k*32+31 = 4 whole bh
    const int wgid = (blockIdx.x & 7) * 32 + (blockIdx.x >> 3);
    const int bh = wgid >> 3;
    const int q0 = (wgid & 7) * 256 + wv * 32;
    const size_t kvb = (size_t)bh * SS * HD;

    // staging coords: each of the 512 threads owns one 16B chunk per array
    const int srow = tid >> 3;          // 0..63
    const int scol = (tid & 7) * 8;     // 0..56

    // q fragments (hi/lo), 2 row-groups x 2 k-chunks (as round 6)
    bf16x8 qh[2][2], ql[2][2];
#pragma unroll
    for (int rg = 0; rg < 2; ++rg) {
        const size_t ro = kvb + (size_t)(q0 + rg * 16 + lr) * HD + lg * 8;
#pragma unroll
        for (int kk = 0; kk < 2; ++kk) {
            qh[rg][kk] = *(const bf16x8*)(qhi_ws + ro + kk * 32);
            ql[rg][kk] = *(const bf16x8*)(qlo_ws + ro + kk * 32);
        }
    }

    const __bf16* khp = khi_ws + kvb;
    const __bf16* klp = klo_ws + kvb;
    const __bf16* vtp = vt_ws + kvb;

    // ---- pass 1: Z ----
    float z[2][4] = {{0.f,0.f,0.f,0.f},{0.f,0.f,0.f,0.f}};
    bf16x8 sh = *(const bf16x8*)(khp + (size_t)srow * HD + scol);
    bf16x8 sl = *(const bf16x8*)(klp + (size_t)srow * HD + scol);
    for (int jt = 0; jt < 32; ++jt) {
        __syncthreads();                       // all waves done with prev tile
        *(bf16x8*)&KH[srow][scol] = sh;
        *(bf16x8*)&KL[srow][scol] = sl;
        __syncthreads();
        if (jt + 1 < 32) {                     // prefetch next tile into regs
            const size_t ro = ((size_t)(jt + 1) * 64 + srow) * HD + scol;
            sh = *(const bf16x8*)(khp + ro);
            sl = *(const bf16x8*)(klp + ro);
        }
#pragma unroll
        for (int cg = 0; cg < 4; ++cg) {
            const bf16x8 kh0 = *(const bf16x8*)&KH[cg * 16 + lr][lg * 8];
            const bf16x8 kh1 = *(const bf16x8*)&KH[cg * 16 + lr][32 + lg * 8];
            const bf16x8 kl0 = *(const bf16x8*)&KL[cg * 16 + lr][lg * 8];
            const bf16x8 kl1 = *(const bf16x8*)&KL[cg * 16 + lr][32 + lg * 8];
#pragma unroll
            for (int rg = 0; rg < 2; ++rg) {
                f32x4 u = (f32x4){0.f, 0.f, 0.f, 0.f};
                u = __builtin_amdgcn_mfma_f32_16x16x32_bf16(qh[rg][0], kh0, u, 0, 0, 0);
                u = __builtin_amdgcn_mfma_f32_16x16x32_bf16(qh[rg][1], kh1, u, 0, 0, 0);
                u = __builtin_amdgcn_mfma_f32_16x16x32_bf16(ql[rg][0], kh0, u, 0, 0, 0);
                u = __builtin_amdgcn_mfma_f32_16x16x32_bf16(ql[rg][1], kh1, u, 0, 0, 0);
                u = __builtin_amdgcn_mfma_f32_16x16x32_bf16(qh[rg][0], kl0, u, 0, 0, 0);
                u = __builtin_amdgcn_mfma_f32_16x16x32_bf16(qh[rg][1], kl1, u, 0, 0, 0);
#pragma unroll
                for (int r = 0; r < 4; ++r) z[rg][r] += __expf(u[r]);
            }
        }
    }
    // butterfly over the 16 lr lanes -> every lane holds Z for its rows
#pragma unroll
    for (int m = 1; m < 16; m <<= 1)
#pragma unroll
        for (int rg = 0; rg < 2; ++rg)
#pragma unroll
            for (int r = 0; r < 4; ++r) z[rg][r] += __shfl_xor(z[rg][r], m, 64);
    float rz[2][4];
#pragma unroll
    for (int rg = 0; rg < 2; ++rg)
#pragma unroll
        for (int r = 0; r < 4; ++r) rz[rg][r] = 1.0f / z[rg][r];

    // ---- pass 2: weights + PV ----
    f32x4 pv[2][4];
#pragma unroll
    for (int rg = 0; rg < 2; ++rg)
#pragma unroll
        for (int dg = 0; dg < 4; ++dg) pv[rg][dg] = (f32x4){0.f, 0.f, 0.f, 0.f};

    float* wbase = wts + ((size_t)bh * SS + q0) * SS;

    sh = *(const bf16x8*)(khp + (size_t)srow * HD + scol);
    sl = *(const bf16x8*)(klp + (size_t)srow * HD + scol);
    bf16x8 sv = *(const bf16x8*)(vtp + (size_t)srow * SS + scol);
    for (int jt = 0; jt < 32; ++jt) {
        const int j0 = jt * 64;
        __syncthreads();
        *(bf16x8*)&KH[srow][scol] = sh;
        *(bf16x8*)&KL[srow][scol] = sl;
        *(bf16x8*)&VTS[srow][scol] = sv;
        __syncthreads();
        if (jt + 1 < 32) {
            const size_t ro = ((size_t)(jt + 1) * 64 + srow) * HD + scol;
            sh = *(const bf16x8*)(khp + ro);
            sl = *(const bf16x8*)(klp + ro);
            sv = *(const bf16x8*)(vtp + (size_t)srow * SS + j0 + 64 + scol);
        }
        // QK + exp -> normalized P (bf16) in wave-private LDS strip
#pragma unroll
        for (int cg = 0; cg < 4; ++cg) {
            const bf16x8 kh0 = *(const bf16x8*)&KH[cg * 16 + lr][lg * 8];
            const bf16x8 kh1 = *(const bf16x8*)&KH[cg * 16 + lr][32 + lg * 8];
            const bf16x8 kl0 = *(const bf16x8*)&KL[cg * 16 + lr][lg * 8];
            const bf16x8 kl1 = *(const bf16x8*)&KL[cg * 16 + lr][32 + lg * 8];
#pragma unroll
            for (int rg = 0; rg < 2; ++rg) {
                f32x4 u = (f32x4){0.f, 0.f, 0.f, 0.f};
                u = __builtin_amdgcn_mfma_f32_16x16x32_bf16(qh[rg][0], kh0, u, 0, 0, 0);
                u = __builtin_amdgcn_mfma_f32_16x16x32_bf16(qh[rg][1], kh1, u, 0, 0, 0);
                u = __builtin_amdgcn_mfma_f32_16x16x32_bf16(ql[rg][0], kh0, u, 0, 0, 0);
                u = __builtin_amdgcn_mfma_f32_16x16x32_bf16(ql[rg][1], kh1, u, 0, 0, 0);
                u = __builtin_amdgcn_mfma_f32_16x16x32_bf16(qh[rg][0], kl0, u, 0, 0, 0);
                u = __builtin_amdgcn_mfma_f32_16x16x32_bf16(qh[rg][1], kl1, u, 0, 0, 0);
#pragma unroll
                for (int r = 0; r < 4; ++r)
                    P[wv][rg * 16 + lg * 4 + r][cg * 16 + lr] =
                        (__bf16)(__expf(u[r]) * rz[rg][r]);
            }
        }
        // PV from staged V + P strip
        {
            bf16x8 vb[4][2];
#pragma unroll
            for (int dg = 0; dg < 4; ++dg)
#pragma unroll
                for (int kk = 0; kk < 2; ++kk)
                    vb[dg][kk] = *(const bf16x8*)&VTS[dg * 16 + lr][kk * 32 + lg * 8];
#pragma unroll
            for (int rg = 0; rg < 2; ++rg) {
                const bf16x8 pa0 = *(const bf16x8*)&P[wv][rg * 16 + lr][lg * 8];
                const bf16x8 pa1 = *(const bf16x8*)&P[wv][rg * 16 + lr][32 + lg * 8];
#pragma unroll
                for (int dg = 0; dg < 4; ++dg) {
                    pv[rg][dg] = __builtin_amdgcn_mfma_f32_16x16x32_bf16(pa0, vb[dg][0], pv[rg][dg], 0, 0, 0);
                    pv[rg][dg] = __builtin_amdgcn_mfma_f32_16x16x32_bf16(pa1, vb[dg][1], pv[rg][dg], 0, 0, 0);
                }
            }
        }
        // weights: fp32 stores from the P strip (bf16-rounded, as round 6)
#pragma unroll
        for (int it = 0; it < 8; ++it) {
            const int row = it * 4 + lg;
            const bf16x4 u = *(const bf16x4*)&P[wv][row][lr * 4];
            float4 o;
            o.x = (float)u[0]; o.y = (float)u[1]; o.z = (float)u[2]; o.w = (float)u[3];
            *(float4*)(wbase + (size_t)row * SS + j0 + lr * 4) = o;
        }
    }

    {   // av -> bf16 ws [B][S][E]
        const int b = bh >> 4, h = bh & 15;
#pragma unroll
        for (int rg = 0; rg < 2; ++rg)
#pragma unroll
            for (int dg = 0; dg < 4; ++dg)
#pragma unroll
                for (int r = 0; r < 4; ++r) {
                    const int s = q0 + rg * 16 + lg * 4 + r;
                    av_ws[((size_t)(b * SS + s)) * EE + h * HD + dg * 16 + lr] =
                        (__bf16)pv[rg][dg][r];
                }
    }
}

// ---------------- K3: out projection (plain bf16) -------------------------
__global__ __launch_bounds__(256) void k_oproj(
    const __bf16* __restrict__ av_ws, const float* __restrict__ w_out,
    const float* __restrict__ b_out, float* __restrict__ out)
{
    __shared__ __bf16 Abf[128][72];
    __shared__ __bf16 Bbf[64][72];
    const int tid = threadIdx.x;
    const int lane = tid & 63;
    const int wv = tid >> 6;
    const int m0 = blockIdx.y * 128, f0 = blockIdx.x * 64;
    const int wr = (wv >> 1) * 64, wc = (wv & 1) * 32;
    const int lr = lane & 15, lg = lane >> 4;

    f32x4 acc[4][2];
#pragma unroll
    for (int a = 0; a < 4; ++a)
#pragma unroll
        for (int b = 0; b < 2; ++b) acc[a][b] = (f32x4){0.f, 0.f, 0.f, 0.f};

    for (int kt = 0; kt < 16; ++kt) {
        const int k0 = kt * 64;
        __syncthreads();
        {
            const int c = tid & 7, r0 = tid >> 3;
#pragma unroll
            for (int i = 0; i < 4; ++i) {
                const int row = r0 + i * 32;
                *(bf16x8*)&Abf[row][c * 8] =
                    *(const bf16x8*)(av_ws + (size_t)(m0 + row) * EE + k0 + c * 8);
            }
        }
        {
            const int c = tid & 15, r0 = tid >> 4;
#pragma unroll
            for (int i = 0; i < 4; ++i) {
                const int row = r0 + i * 16;
                const float4 v = *(const float4*)(w_out + (size_t)(f0 + row) * EE + k0 + c * 4);
                bf16x4 pk;
                pk[0] = (__bf16)v.x; pk[1] = (__bf16)v.y;
                pk[2] = (__bf16)v.z; pk[3] = (__bf16)v.w;
                *(bf16x4*)&Bbf[row][c * 4] = pk;
            }
        }
        __syncthreads();
#pragma unroll
        for (int ks = 0; ks < 2; ++ks) {
            const int koff = ks * 32 + lg * 8;
            bf16x8 a[4], b[2];
#pragma unroll
            for (int rt = 0; rt < 4; ++rt) a[rt] = *(const bf16x8*)&Abf[wr + rt * 16 + lr][koff];
#pragma unroll
            for (int ct = 0; ct < 2; ++ct) b[ct] = *(const bf16x8*)&Bbf[wc + ct * 16 + lr][koff];
#pragma unroll
            for (int rt = 0; rt < 4; ++rt)
#pragma unroll
                for (int ct = 0; ct < 2; ++ct)
                    acc[rt][ct] = __builtin_amdgcn_mfma_f32_16x16x32_bf16(a[rt], b[ct], acc[rt][ct], 0, 0, 0);
        }
    }
#pragma unroll
    for (int rt = 0; rt < 4; ++rt) {
        const int m = m0 + wr + rt * 16 + lg * 4;
#pragma unroll
        for (int ct = 0; ct < 2; ++ct) {
            const int f = f0 + wc + ct * 16 + lr;
            const float bo = b_out[f];
#pragma unroll
            for (int r = 0; r < 4; ++r)
                out[(size_t)(m + r) * EE + f] = acc[rt][ct][r] + bo;
        }
    }
}

extern "C" void kernel_launch(void* const* d_in, const int* in_sizes, int n_in,
                              void* d_out, int out_size, void* d_ws, size_t ws_size,
                              hipStream_t stream)
{
    const float* x    = (const float*)d_in[0];
    const float* wqkv = (const float*)d_in[1];
    const float* bqkv = (const float*)d_in[2];
    const float* wo   = (const float*)d_in[3];
    const float* bo   = (const float*)d_in[4];
    const float* rel  = (const float*)d_in[5];

    float* out = (float*)d_out;
    float* wts = out + (size_t)BB * SS * EE;      // weights region, written by K2

    const size_t NQ = (size_t)BB * HH * SS * HD;  // 4M elements
    __bf16* qhi_ws = (__bf16*)d_ws;               // 8 MB each
    __bf16* qlo_ws = qhi_ws + NQ;
    __bf16* khi_ws = qlo_ws + NQ;
    __bf16* klo_ws = khi_ws + NQ;
    __bf16* vt_ws  = klo_ws + NQ;
    __bf16* av_ws  = vt_ws + NQ;                  // ws total: 48 MB

    // hi/lo splits of x and w_qkv live in the weights output region:
    // fully consumed by K1 before K2 overwrites it. (28 MB of 512 MB.)
    __bf16* xhi = (__bf16*)wts;
    __bf16* xlo = xhi + (size_t)BB * SS * EE;
    __bf16* whi = xlo + (size_t)BB * SS * EE;
    __bf16* wlo = whi + (size_t)3 * EE * EE;

    k_split<<<dim3((BB * SS * EE) / 1024), 256, 0, stream>>>(x, xhi, xlo, (BB * SS * EE) / 4);
    k_split<<<dim3((3 * EE * EE) / 1024), 256, 0, stream>>>(wqkv, whi, wlo, (3 * EE * EE) / 4);
    k_qkv<<<dim3(48, 32), 256, 0, stream>>>(xhi, xlo, whi, wlo, bqkv, rel,
                                            qhi_ws, qlo_ws, khi_ws, klo_ws, vt_ws);
    k_attn7<<<dim3(256), 512, 0, stream>>>(qhi_ws, qlo_ws, khi_ws, klo_ws,
                                           vt_ws, wts, av_ws);
    k_oproj<<<dim3(EE / 64, (BB * SS) / 128), 256, 0, stream>>>(av_ws, wo, bo, out);
}

// Round 9
// 297.621 us; speedup vs baseline: 1.6621x; 1.1517x over previous
//
#include <hip/hip_runtime.h>
#include <hip/hip_bf16.h>

#define BB 2
#define SS 2048
#define EE 1024
#define HH 16
#define HD 64

typedef __attribute__((ext_vector_type(8))) __bf16 bf16x8;
typedef __attribute__((ext_vector_type(4))) __bf16 bf16x4;
typedef __attribute__((ext_vector_type(4))) float f32x4;

__device__ __forceinline__ void split2(float x, __bf16& h, __bf16& l) {
    h = (__bf16)x;                 // RTNE
    l = (__bf16)(x - (float)h);    // residual
}

// ---------------- K1: QKV projection, fused fp32->hi/lo split staging -----
// Reads x and w_qkv fp32 directly; splits to bf16 hi/lo in-register during
// LDS staging. 3-term split GEMM, fp32-accurate.
// q,k' emitted PRE-SPLIT bf16 hi/lo; k' = k/8 + rel; v transposed bf16.
__global__ __launch_bounds__(256) void k_qkv(
    const float* __restrict__ xx, const float* __restrict__ ww,
    const float* __restrict__ bqkv, const float* __restrict__ rel,
    __bf16* __restrict__ qhi_ws, __bf16* __restrict__ qlo_ws,
    __bf16* __restrict__ khi_ws, __bf16* __restrict__ klo_ws,
    __bf16* __restrict__ vt_ws)
{
    __shared__ __bf16 Ahi[128][72], Alo[128][72];
    __shared__ __bf16 Bhi[64][72],  Blo[64][72];

    const int tid = threadIdx.x;
    const int lane = tid & 63;
    const int wv = tid >> 6;
    const int m0 = blockIdx.y * 128;
    const int f0 = blockIdx.x * 64;
    const int wr = (wv >> 1) * 64, wc = (wv & 1) * 32;
    const int lr = lane & 15, lg = lane >> 4;

    f32x4 acc[4][2];
#pragma unroll
    for (int a = 0; a < 4; ++a)
#pragma unroll
        for (int b = 0; b < 2; ++b) acc[a][b] = (f32x4){0.f, 0.f, 0.f, 0.f};

    for (int kt = 0; kt < 16; ++kt) {
        const int k0 = kt * 64;
        __syncthreads();
        {   // stage A tile 128x64: fp32 load -> split -> hi/lo LDS
            const int c = tid & 7, r0 = tid >> 3;
#pragma unroll
            for (int i = 0; i < 4; ++i) {
                const int row = r0 + i * 32;
                const float* gp = xx + (size_t)(m0 + row) * EE + k0 + c * 8;
                const float4 v0 = *(const float4*)gp;
                const float4 v1 = *(const float4*)(gp + 4);
                float t[8] = {v0.x, v0.y, v0.z, v0.w, v1.x, v1.y, v1.z, v1.w};
                bf16x8 hi, lo;
#pragma unroll
                for (int e = 0; e < 8; ++e) {
                    __bf16 h, l; split2(t[e], h, l);
                    hi[e] = h; lo[e] = l;
                }
                *(bf16x8*)&Ahi[row][c * 8] = hi;
                *(bf16x8*)&Alo[row][c * 8] = lo;
            }
        }
        {   // stage B tile 64x64: fp32 load -> split -> hi/lo LDS
            const int c = tid & 7, r0 = tid >> 3;
#pragma unroll
            for (int i = 0; i < 2; ++i) {
                const int row = r0 + i * 32;
                const float* gp = ww + (size_t)(f0 + row) * EE + k0 + c * 8;
                const float4 v0 = *(const float4*)gp;
                const float4 v1 = *(const float4*)(gp + 4);
                float t[8] = {v0.x, v0.y, v0.z, v0.w, v1.x, v1.y, v1.z, v1.w};
                bf16x8 hi, lo;
#pragma unroll
                for (int e = 0; e < 8; ++e) {
                    __bf16 h, l; split2(t[e], h, l);
                    hi[e] = h; lo[e] = l;
                }
                *(bf16x8*)&Bhi[row][c * 8] = hi;
                *(bf16x8*)&Blo[row][c * 8] = lo;
            }
        }
        __syncthreads();
#pragma unroll
        for (int ks = 0; ks < 2; ++ks) {
            const int koff = ks * 32 + lg * 8;
            bf16x8 ah[4], al[4], bh[2], bl[2];
#pragma unroll
            for (int rt = 0; rt < 4; ++rt) {
                ah[rt] = *(const bf16x8*)&Ahi[wr + rt * 16 + lr][koff];
                al[rt] = *(const bf16x8*)&Alo[wr + rt * 16 + lr][koff];
            }
#pragma unroll
            for (int ct = 0; ct < 2; ++ct) {
                bh[ct] = *(const bf16x8*)&Bhi[wc + ct * 16 + lr][koff];
                bl[ct] = *(const bf16x8*)&Blo[wc + ct * 16 + lr][koff];
            }
#pragma unroll
            for (int rt = 0; rt < 4; ++rt)
#pragma unroll
                for (int ct = 0; ct < 2; ++ct) {
                    acc[rt][ct] = __builtin_amdgcn_mfma_f32_16x16x32_bf16(ah[rt], bh[ct], acc[rt][ct], 0, 0, 0);
                    acc[rt][ct] = __builtin_amdgcn_mfma_f32_16x16x32_bf16(al[rt], bh[ct], acc[rt][ct], 0, 0, 0);
                    acc[rt][ct] = __builtin_amdgcn_mfma_f32_16x16x32_bf16(ah[rt], bl[ct], acc[rt][ct], 0, 0, 0);
                }
        }
    }

    const int blk = f0 >> 6;             // 0..47
    const int h = blk / 3, typ = blk % 3;
#pragma unroll
    for (int rt = 0; rt < 4; ++rt) {
        const int m = m0 + wr + rt * 16 + lg * 4;
        const int b = m >> 11, s = m & 2047;
#pragma unroll
        for (int ct = 0; ct < 2; ++ct) {
            const int d = wc + ct * 16 + lr;
            const float bq = bqkv[f0 + d];
            if (typ == 0) {
                const size_t base = ((size_t)(b * HH + h) * SS + s) * HD + d;
#pragma unroll
                for (int r = 0; r < 4; ++r) {
                    __bf16 hh, ll; split2(acc[rt][ct][r] + bq, hh, ll);
                    qhi_ws[base + (size_t)r * HD] = hh;
                    qlo_ws[base + (size_t)r * HD] = ll;
                }
            } else if (typ == 1) {
                const size_t base = ((size_t)(b * HH + h) * SS + s) * HD + d;
                const size_t rb = ((size_t)h * SS + s) * HD + d;
#pragma unroll
                for (int r = 0; r < 4; ++r) {
                    const float t = (acc[rt][ct][r] + bq) * 0.125f + rel[rb + (size_t)r * HD];
                    __bf16 hh, ll; split2(t, hh, ll);
                    khi_ws[base + (size_t)r * HD] = hh;
                    klo_ws[base + (size_t)r * HD] = ll;
                }
            } else {
                const size_t base = ((size_t)(b * HH + h) * HD + d) * SS + s;
                bf16x4 pk;
#pragma unroll
                for (int r = 0; r < 4; ++r) pk[r] = (__bf16)(acc[rt][ct][r] + bq);
                *(bf16x4*)&vt_ws[base] = pk;
            }
        }
    }
}

// ---------------- K2: two-pass attention, dbuf staging + nt stores --------
// As round 7 (block-shared K/V in LDS, 8 waves x 32 q-rows, one bh/block)
// plus: (1) double-buffered staging -> ONE barrier per j-tile; (2) weights
// written with non-temporal stores (532 MB stream bypasses L2). Numerics
// identical to round 7.
__global__ __launch_bounds__(512, 1) void k_attn8(
    const __bf16* __restrict__ qhi_ws, const __bf16* __restrict__ qlo_ws,
    const __bf16* __restrict__ khi_ws, const __bf16* __restrict__ klo_ws,
    const __bf16* __restrict__ vt_ws,
    float* __restrict__ wts, __bf16* __restrict__ av_ws)
{
    __shared__ __bf16 KH[2][64][72], KL[2][64][72], VTS[2][64][72]; // 55.3 KB
    __shared__ __bf16 P[8][32][72];                                 // 36.9 KB

    const int tid = threadIdx.x;
    const int lane = tid & 63;
    const int wv = tid >> 6;          // 0..7
    const int lr = lane & 15, lg = lane >> 4;

    // XCD swizzle: 256 blocks; XCD k gets wgid k*32..k*32+31 = 4 whole bh
    const int wgid = (blockIdx.x & 7) * 32 + (blockIdx.x >> 3);
    const int bh = wgid >> 3;
    const int q0 = (wgid & 7) * 256 + wv * 32;
    const size_t kvb = (size_t)bh * SS * HD;

    const int srow = tid >> 3;          // 0..63
    const int scol = (tid & 7) * 8;     // 0..56

    // q fragments (hi/lo), 2 row-groups x 2 k-chunks
    bf16x8 qh[2][2], ql[2][2];
#pragma unroll
    for (int rg = 0; rg < 2; ++rg) {
        const size_t ro = kvb + (size_t)(q0 + rg * 16 + lr) * HD + lg * 8;
#pragma unroll
        for (int kk = 0; kk < 2; ++kk) {
            qh[rg][kk] = *(const bf16x8*)(qhi_ws + ro + kk * 32);
            ql[rg][kk] = *(const bf16x8*)(qlo_ws + ro + kk * 32);
        }
    }

    const __bf16* khp = khi_ws + kvb;
    const __bf16* klp = klo_ws + kvb;
    const __bf16* vtp = vt_ws + kvb;

    // ---- pass 1: Z ----
    float z[2][4] = {{0.f,0.f,0.f,0.f},{0.f,0.f,0.f,0.f}};
    {
        bf16x8 sh = *(const bf16x8*)(khp + (size_t)srow * HD + scol);
        bf16x8 sl = *(const bf16x8*)(klp + (size_t)srow * HD + scol);
        *(bf16x8*)&KH[0][srow][scol] = sh;
        *(bf16x8*)&KL[0][srow][scol] = sl;
        __syncthreads();
        for (int jt = 0; jt < 32; ++jt) {
            const int cur = jt & 1;
            if (jt + 1 < 32) {               // prefetch next tile into regs
                const size_t ro = ((size_t)(jt + 1) * 64 + srow) * HD + scol;
                sh = *(const bf16x8*)(khp + ro);
                sl = *(const bf16x8*)(klp + ro);
            }
#pragma unroll
            for (int cg = 0; cg < 4; ++cg) {
                const bf16x8 kh0 = *(const bf16x8*)&KH[cur][cg * 16 + lr][lg * 8];
                const bf16x8 kh1 = *(const bf16x8*)&KH[cur][cg * 16 + lr][32 + lg * 8];
                const bf16x8 kl0 = *(const bf16x8*)&KL[cur][cg * 16 + lr][lg * 8];
                const bf16x8 kl1 = *(const bf16x8*)&KL[cur][cg * 16 + lr][32 + lg * 8];
#pragma unroll
                for (int rg = 0; rg < 2; ++rg) {
                    f32x4 u = (f32x4){0.f, 0.f, 0.f, 0.f};
                    u = __builtin_amdgcn_mfma_f32_16x16x32_bf16(qh[rg][0], kh0, u, 0, 0, 0);
                    u = __builtin_amdgcn_mfma_f32_16x16x32_bf16(qh[rg][1], kh1, u, 0, 0, 0);
                    u = __builtin_amdgcn_mfma_f32_16x16x32_bf16(ql[rg][0], kh0, u, 0, 0, 0);
                    u = __builtin_amdgcn_mfma_f32_16x16x32_bf16(ql[rg][1], kh1, u, 0, 0, 0);
                    u = __builtin_amdgcn_mfma_f32_16x16x32_bf16(qh[rg][0], kl0, u, 0, 0, 0);
                    u = __builtin_amdgcn_mfma_f32_16x16x32_bf16(qh[rg][1], kl1, u, 0, 0, 0);
#pragma unroll
                    for (int r = 0; r < 4; ++r) z[rg][r] += __expf(u[r]);
                }
            }
            if (jt + 1 < 32) {               // stage next tile (regs -> LDS)
                *(bf16x8*)&KH[cur ^ 1][srow][scol] = sh;
                *(bf16x8*)&KL[cur ^ 1][srow][scol] = sl;
            }
            __syncthreads();
        }
    }
    // butterfly over the 16 lr lanes -> every lane holds Z for its rows
#pragma unroll
    for (int m = 1; m < 16; m <<= 1)
#pragma unroll
        for (int rg = 0; rg < 2; ++rg)
#pragma unroll
            for (int r = 0; r < 4; ++r) z[rg][r] += __shfl_xor(z[rg][r], m, 64);
    float rz[2][4];
#pragma unroll
    for (int rg = 0; rg < 2; ++rg)
#pragma unroll
        for (int r = 0; r < 4; ++r) rz[rg][r] = 1.0f / z[rg][r];

    // ---- pass 2: weights + PV ----
    f32x4 pv[2][4];
#pragma unroll
    for (int rg = 0; rg < 2; ++rg)
#pragma unroll
        for (int dg = 0; dg < 4; ++dg) pv[rg][dg] = (f32x4){0.f, 0.f, 0.f, 0.f};

    float* wbase = wts + ((size_t)bh * SS + q0) * SS;

    {
        bf16x8 sh = *(const bf16x8*)(khp + (size_t)srow * HD + scol);
        bf16x8 sl = *(const bf16x8*)(klp + (size_t)srow * HD + scol);
        bf16x8 sv = *(const bf16x8*)(vtp + (size_t)srow * SS + scol);
        *(bf16x8*)&KH[0][srow][scol] = sh;
        *(bf16x8*)&KL[0][srow][scol] = sl;
        *(bf16x8*)&VTS[0][srow][scol] = sv;
        __syncthreads();
        for (int jt = 0; jt < 32; ++jt) {
            const int cur = jt & 1;
            const int j0 = jt * 64;
            if (jt + 1 < 32) {
                const size_t ro = ((size_t)(jt + 1) * 64 + srow) * HD + scol;
                sh = *(const bf16x8*)(khp + ro);
                sl = *(const bf16x8*)(klp + ro);
                sv = *(const bf16x8*)(vtp + (size_t)srow * SS + j0 + 64 + scol);
            }
            // QK + exp -> normalized P (bf16) in wave-private LDS strip
#pragma unroll
            for (int cg = 0; cg < 4; ++cg) {
                const bf16x8 kh0 = *(const bf16x8*)&KH[cur][cg * 16 + lr][lg * 8];
                const bf16x8 kh1 = *(const bf16x8*)&KH[cur][cg * 16 + lr][32 + lg * 8];
                const bf16x8 kl0 = *(const bf16x8*)&KL[cur][cg * 16 + lr][lg * 8];
                const bf16x8 kl1 = *(const bf16x8*)&KL[cur][cg * 16 + lr][32 + lg * 8];
#pragma unroll
                for (int rg = 0; rg < 2; ++rg) {
                    f32x4 u = (f32x4){0.f, 0.f, 0.f, 0.f};
                    u = __builtin_amdgcn_mfma_f32_16x16x32_bf16(qh[rg][0], kh0, u, 0, 0, 0);
                    u = __builtin_amdgcn_mfma_f32_16x16x32_bf16(qh[rg][1], kh1, u, 0, 0, 0);
                    u = __builtin_amdgcn_mfma_f32_16x16x32_bf16(ql[rg][0], kh0, u, 0, 0, 0);
                    u = __builtin_amdgcn_mfma_f32_16x16x32_bf16(ql[rg][1], kh1, u, 0, 0, 0);
                    u = __builtin_amdgcn_mfma_f32_16x16x32_bf16(qh[rg][0], kl0, u, 0, 0, 0);
                    u = __builtin_amdgcn_mfma_f32_16x16x32_bf16(qh[rg][1], kl1, u, 0, 0, 0);
#pragma unroll
                    for (int r = 0; r < 4; ++r)
                        P[wv][rg * 16 + lg * 4 + r][cg * 16 + lr] =
                            (__bf16)(__expf(u[r]) * rz[rg][r]);
                }
            }
            // PV from staged V + P strip
            {
                bf16x8 vb[4][2];
#pragma unroll
                for (int dg = 0; dg < 4; ++dg)
#pragma unroll
                    for (int kk = 0; kk < 2; ++kk)
                        vb[dg][kk] = *(const bf16x8*)&VTS[cur][dg * 16 + lr][kk * 32 + lg * 8];
#pragma unroll
                for (int rg = 0; rg < 2; ++rg) {
                    const bf16x8 pa0 = *(const bf16x8*)&P[wv][rg * 16 + lr][lg * 8];
                    const bf16x8 pa1 = *(const bf16x8*)&P[wv][rg * 16 + lr][32 + lg * 8];
#pragma unroll
                    for (int dg = 0; dg < 4; ++dg) {
                        pv[rg][dg] = __builtin_amdgcn_mfma_f32_16x16x32_bf16(pa0, vb[dg][0], pv[rg][dg], 0, 0, 0);
                        pv[rg][dg] = __builtin_amdgcn_mfma_f32_16x16x32_bf16(pa1, vb[dg][1], pv[rg][dg], 0, 0, 0);
                    }
                }
            }
            // weights: non-temporal fp32 stores (native vector type) from P
#pragma unroll
            for (int it = 0; it < 8; ++it) {
                const int row = it * 4 + lg;
                const bf16x4 u = *(const bf16x4*)&P[wv][row][lr * 4];
                f32x4 o;
                o[0] = (float)u[0]; o[1] = (float)u[1];
                o[2] = (float)u[2]; o[3] = (float)u[3];
                __builtin_nontemporal_store(o, (f32x4*)(wbase + (size_t)row * SS + j0 + lr * 4));
            }
            // stage next tile (regs -> LDS), then single barrier
            if (jt + 1 < 32) {
                *(bf16x8*)&KH[cur ^ 1][srow][scol] = sh;
                *(bf16x8*)&KL[cur ^ 1][srow][scol] = sl;
                *(bf16x8*)&VTS[cur ^ 1][srow][scol] = sv;
            }
            __syncthreads();
        }
    }

    {   // av -> bf16 ws [B][S][E]
        const int b = bh >> 4, h = bh & 15;
#pragma unroll
        for (int rg = 0; rg < 2; ++rg)
#pragma unroll
            for (int dg = 0; dg < 4; ++dg)
#pragma unroll
                for (int r = 0; r < 4; ++r) {
                    const int s = q0 + rg * 16 + lg * 4 + r;
                    av_ws[((size_t)(b * SS + s)) * EE + h * HD + dg * 16 + lr] =
                        (__bf16)pv[rg][dg][r];
                }
    }
}

// ---------------- K3: out projection (plain bf16) -------------------------
__global__ __launch_bounds__(256) void k_oproj(
    const __bf16* __restrict__ av_ws, const float* __restrict__ w_out,
    const float* __restrict__ b_out, float* __restrict__ out)
{
    __shared__ __bf16 Abf[128][72];
    __shared__ __bf16 Bbf[64][72];
    const int tid = threadIdx.x;
    const int lane = tid & 63;
    const int wv = tid >> 6;
    const int m0 = blockIdx.y * 128, f0 = blockIdx.x * 64;
    const int wr = (wv >> 1) * 64, wc = (wv & 1) * 32;
    const int lr = lane & 15, lg = lane >> 4;

    f32x4 acc[4][2];
#pragma unroll
    for (int a = 0; a < 4; ++a)
#pragma unroll
        for (int b = 0; b < 2; ++b) acc[a][b] = (f32x4){0.f, 0.f, 0.f, 0.f};

    for (int kt = 0; kt < 16; ++kt) {
        const int k0 = kt * 64;
        __syncthreads();
        {
            const int c = tid & 7, r0 = tid >> 3;
#pragma unroll
            for (int i = 0; i < 4; ++i) {
                const int row = r0 + i * 32;
                *(bf16x8*)&Abf[row][c * 8] =
                    *(const bf16x8*)(av_ws + (size_t)(m0 + row) * EE + k0 + c * 8);
            }
        }
        {
            const int c = tid & 15, r0 = tid >> 4;
#pragma unroll
            for (int i = 0; i < 4; ++i) {
                const int row = r0 + i * 16;
                const float4 v = *(const float4*)(w_out + (size_t)(f0 + row) * EE + k0 + c * 4);
                bf16x4 pk;
                pk[0] = (__bf16)v.x; pk[1] = (__bf16)v.y;
                pk[2] = (__bf16)v.z; pk[3] = (__bf16)v.w;
                *(bf16x4*)&Bbf[row][c * 4] = pk;
            }
        }
        __syncthreads();
#pragma unroll
        for (int ks = 0; ks < 2; ++ks) {
            const int koff = ks * 32 + lg * 8;
            bf16x8 a[4], b[2];
#pragma unroll
            for (int rt = 0; rt < 4; ++rt) a[rt] = *(const bf16x8*)&Abf[wr + rt * 16 + lr][koff];
#pragma unroll
            for (int ct = 0; ct < 2; ++ct) b[ct] = *(const bf16x8*)&Bbf[wc + ct * 16 + lr][koff];
#pragma unroll
            for (int rt = 0; rt < 4; ++rt)
#pragma unroll
                for (int ct = 0; ct < 2; ++ct)
                    acc[rt][ct] = __builtin_amdgcn_mfma_f32_16x16x32_bf16(a[rt], b[ct], acc[rt][ct], 0, 0, 0);
        }
    }
#pragma unroll
    for (int rt = 0; rt < 4; ++rt) {
        const int m = m0 + wr + rt * 16 + lg * 4;
#pragma unroll
        for (int ct = 0; ct < 2; ++ct) {
            const int f = f0 + wc + ct * 16 + lr;
            const float bo = b_out[f];
#pragma unroll
            for (int r = 0; r < 4; ++r)
                __builtin_nontemporal_store(acc[rt][ct][r] + bo,
                                            out + (size_t)(m + r) * EE + f);
        }
    }
}

extern "C" void kernel_launch(void* const* d_in, const int* in_sizes, int n_in,
                              void* d_out, int out_size, void* d_ws, size_t ws_size,
                              hipStream_t stream)
{
    const float* x    = (const float*)d_in[0];
    const float* wqkv = (const float*)d_in[1];
    const float* bqkv = (const float*)d_in[2];
    const float* wo   = (const float*)d_in[3];
    const float* bo   = (const float*)d_in[4];
    const float* rel  = (const float*)d_in[5];

    float* out = (float*)d_out;
    float* wts = out + (size_t)BB * SS * EE;      // weights region, written by K2

    const size_t NQ = (size_t)BB * HH * SS * HD;  // 4M elements
    __bf16* qhi_ws = (__bf16*)d_ws;               // 8 MB each
    __bf16* qlo_ws = qhi_ws + NQ;
    __bf16* khi_ws = qlo_ws + NQ;
    __bf16* klo_ws = khi_ws + NQ;
    __bf16* vt_ws  = klo_ws + NQ;
    __bf16* av_ws  = vt_ws + NQ;                  // ws total: 48 MB

    k_qkv<<<dim3(48, 32), 256, 0, stream>>>(x, wqkv, bqkv, rel,
                                            qhi_ws, qlo_ws, khi_ws, klo_ws, vt_ws);
    k_attn8<<<dim3(256), 512, 0, stream>>>(qhi_ws, qlo_ws, khi_ws, klo_ws,
                                           vt_ws, wts, av_ws);
    k_oproj<<<dim3(EE / 64, (BB * SS) / 128), 256, 0, stream>>>(av_ws, wo, bo, out);
}